// Round 16
// baseline (339.691 us; speedup 1.0000x reference)
//
#include <hip/hip_runtime.h>
#include <hip/hip_bf16.h>
#include <stdint.h>

#define NN 50000
#define NE 800000
#define HD 128
#define NL 3
#define EPS_BN 1e-5f
#define EPS_NORM 1e-12f
#define NEG_SLOPE 0.1f

#define SCAN_CHUNK 256
#define SCAN_BLOCKS ((NN + SCAN_CHUNK - 1) / SCAN_CHUNK)   // 196
#define NTILES ((NN + 127) / 128)                          // 391

#define BSH 9                                   // coarse bucket = dst >> 9 (512 nodes)
#define NB ((NN + (1 << BSH) - 1) >> BSH)       // 98 buckets
#define MAXBE 9728                              // per-bucket edge cap

// prep kernel block ranges
#define PREP_HIST_B ((NE + 255) / 256)                        // 3125
#define PREP_TOB_B  ((NN * 64 + 255) / 256)                   // 12500
#define PREP_PACK_B ((NL * 16384 + 8192 + 255) / 256)         // 224
#define PREP_TOTAL_B (PREP_HIST_B + PREP_TOB_B + PREP_PACK_B)

typedef __attribute__((ext_vector_type(8))) short bf16x8;
typedef __attribute__((ext_vector_type(4))) float f32x4;

static __device__ __forceinline__ unsigned pack_bf16(float a, float b) {
  unsigned ua = __builtin_bit_cast(unsigned, a);
  unsigned ub = __builtin_bit_cast(unsigned, b);
  ua = (ua + 0x7fffu + ((ua >> 16) & 1u)) >> 16;   // RNE
  ub = (ub + 0x7fffu + ((ub >> 16) & 1u)) >> 16;
  return ua | (ub << 16);
}
static __device__ __forceinline__ ushort bf16of(float f) {
  unsigned u = __builtin_bit_cast(unsigned, f);
  u = (u + 0x7fffu + ((u >> 16) & 1u)) >> 16;
  return (ushort)u;
}
static __device__ __forceinline__ float bflo(unsigned u) { return __builtin_bit_cast(float, u << 16); }
static __device__ __forceinline__ float bfhi(unsigned u) { return __builtin_bit_cast(float, u & 0xffff0000u); }

// ---------------- prep: hist + tobf16 + packW + zero counters (merged) ----------------
__global__ __launch_bounds__(256) void prep_kernel(const int* __restrict__ dst,
                                                   const float* __restrict__ x,
                                                   const float* __restrict__ Wl,
                                                   const float* __restrict__ Wr,
                                                   const float* __restrict__ Wsm,
                                                   int* __restrict__ degi,
                                                   ushort* __restrict__ xb,
                                                   unsigned* __restrict__ wpackL,
                                                   unsigned* __restrict__ wpackS,
                                                   int* __restrict__ done_counter) {
  int b = blockIdx.x;
  if (b == 0 && threadIdx.x == 0) *done_counter = 0;
  if (b < PREP_HIST_B) {
    int i = b * 256 + threadIdx.x;
    if (i < NE) atomicAdd(&degi[dst[i]], 1);
  } else if (b < PREP_HIST_B + PREP_TOB_B) {
    int i = (b - PREP_HIST_B) * 256 + threadIdx.x;
    if (i < NN * 64) {
      float2 f = *(const float2*)(x + (size_t)i * 2);
      *(unsigned*)(xb + (size_t)i * 2) = pack_bf16(f.x, f.y);
    }
  } else {
    int i = (b - PREP_HIST_B - PREP_TOB_B) * 256 + threadIdx.x;
    if (i < NL * 16384) {
      int l = i >> 14, rem = i & 16383;
      int c = rem >> 7, kp = rem & 127;
      int k2 = kp * 2;
      float f0, f1;
      if (k2 < HD) { const float* W = Wl + (size_t)l * HD * HD + c * HD + k2; f0 = W[0]; f1 = W[1]; }
      else         { const float* W = Wr + (size_t)l * HD * HD + c * HD + (k2 - HD); f0 = W[0]; f1 = W[1]; }
      unsigned ba = (unsigned)(c * 512 + kp * 4) ^ (unsigned)((c & 7) << 4);
      *(unsigned*)((char*)(wpackL + (size_t)l * 16384) + ba) = pack_bf16(f0, f1);
    } else if (i < NL * 16384 + 8192) {
      int j = i - NL * 16384;
      int c = j >> 6, kp = j & 63;
      int k2 = kp * 2;
      unsigned ba = (unsigned)(c * 256 + kp * 4) ^ (unsigned)((c & 7) << 4);
      *(unsigned*)((char*)wpackS + ba) = pack_bf16(Wsm[c * HD + k2], Wsm[c * HD + k2 + 1]);
    }
  }
}

// ---------------- fused blocksum + blockscan (last block scans) ----------------
__global__ __launch_bounds__(256) void bsum_scan_kernel(const int* __restrict__ degi,
                                                        int* __restrict__ blocksum,
                                                        int* __restrict__ blockoff,
                                                        int* __restrict__ rowptr,
                                                        int* __restrict__ done_counter) {
  __shared__ int sh[256];
  __shared__ int lastflag;
  int t = threadIdx.x;
  int i = blockIdx.x * 256 + t;
  sh[t] = (i < NN) ? degi[i] : 0;
  __syncthreads();
  for (int off = 128; off >= 1; off >>= 1) {
    if (t < off) sh[t] += sh[t + off];
    __syncthreads();
  }
  if (t == 0) {
    blocksum[blockIdx.x] = sh[0];
    __threadfence();
    int ticket = atomicAdd(done_counter, 1);
    lastflag = (ticket == SCAN_BLOCKS - 1) ? 1 : 0;
  }
  __syncthreads();
  if (lastflag) {
    int v = (t < SCAN_BLOCKS) ? blocksum[t] : 0;
    sh[t] = v;
    __syncthreads();
    for (int off = 1; off < 256; off <<= 1) {
      int u = (t >= off) ? sh[t - off] : 0;
      __syncthreads();
      sh[t] += u;
      __syncthreads();
    }
    if (t < SCAN_BLOCKS) blockoff[t] = sh[t] - v;
    if (t == 255) rowptr[NN] = sh[255];
  }
}

// also seeds bcursor[c] = rowptr[c*512]
__global__ __launch_bounds__(256) void chunkscan_kernel(const int* __restrict__ degi,
                                                        const int* __restrict__ blockoff,
                                                        int* __restrict__ rowptr,
                                                        int* __restrict__ bcursor,
                                                        float* __restrict__ invdeg) {
  __shared__ int sh[256];
  int t = threadIdx.x;
  int i = blockIdx.x * 256 + t;
  int d = (i < NN) ? degi[i] : 0;
  sh[t] = d;
  __syncthreads();
  for (int off = 1; off < 256; off <<= 1) {
    int u = (t >= off) ? sh[t - off] : 0;
    __syncthreads();
    sh[t] += u;
    __syncthreads();
  }
  if (i < NN) {
    int pre = blockoff[blockIdx.x] + sh[t] - d;
    rowptr[i] = pre;
    if ((i & ((1 << BSH) - 1)) == 0) bcursor[i >> BSH] = pre;
    invdeg[i] = 1.0f / fmaxf((float)d, 1.0f);
  }
}

// ---------------- degree-sorted node permutation (1 block counting sort, 64 bins) ----------------
__global__ __launch_bounds__(1024) void degsort_kernel(const int* __restrict__ degi,
                                                       int* __restrict__ perm) {
  __shared__ int bins[64];
  __shared__ int base[64];
  int t = threadIdx.x;
  if (t < 64) bins[t] = 0;
  __syncthreads();
  for (int i = t; i < NN; i += 1024) atomicAdd(&bins[min(degi[i], 63)], 1);
  __syncthreads();
  if (t == 0) {
    int run = 0;
    for (int b = 0; b < 64; ++b) { base[b] = run; run += bins[b]; bins[b] = 0; }
  }
  __syncthreads();
  for (int i = t; i < NN; i += 1024) {
    int b = min(degi[i], 63);
    int pos = base[b] + atomicAdd(&bins[b], 1);
    perm[pos] = i;
  }
}

// ---------------- Phase B: group edges by coarse bucket ----------------
__global__ __launch_bounds__(1024) void bucketB_kernel(const int* __restrict__ src,
                                                       const int* __restrict__ dst,
                                                       int* __restrict__ bcursor,
                                                       uint2* __restrict__ bpack) {
  __shared__ int hist[NB], lstart[NB], gbase[NB];
  __shared__ uint2 sdat[1024];
  const int tid = threadIdx.x;
  const int e = blockIdx.x * 1024 + tid;
  if (tid < NB) hist[tid] = 0;
  __syncthreads();
  int s = 0, d = 0, b = 0, myIdx = 0;
  bool valid = (e < NE);
  if (valid) {
    s = src[e];
    d = dst[e];
    b = d >> BSH;
    myIdx = atomicAdd(&hist[b], 1);
  }
  __syncthreads();
  if (tid == 0) {
    int run = 0;
    for (int i = 0; i < NB; ++i) { lstart[i] = run; run += hist[i]; }
  }
  __syncthreads();
  if (tid < NB && hist[tid] > 0) gbase[tid] = atomicAdd(&bcursor[tid], hist[tid]);
  __syncthreads();
  if (valid) sdat[lstart[b] + myIdx] = make_uint2((unsigned)s, (unsigned)d);
  __syncthreads();
  int tot = lstart[NB - 1] + hist[NB - 1];
  if (tid < tot) {
    uint2 p = sdat[tid];
    int bb = (int)(p.y >> BSH);
    bpack[gbase[bb] + (tid - lstart[bb])] = p;
  }
}

// ---------------- Phase C: per-bucket LDS counting sort -> contiguous esrc ----------------
__global__ __launch_bounds__(1024) void bucketC_kernel(const int* __restrict__ rowptr,
                                                       const uint2* __restrict__ bpack,
                                                       int* __restrict__ esrc) {
  __shared__ int lcur[1 << BSH];
  __shared__ int lsrc[MAXBE];
  const int c = blockIdx.x, tid = threadIdx.x;
  const int nbase = c << BSH;
  const int nend = min(nbase + (1 << BSH), NN);
  const int ebase = rowptr[nbase];
  const int cnt = rowptr[nend] - ebase;
  if (tid < (1 << BSH)) {
    int n = nbase + tid;
    lcur[tid] = (n < nend) ? rowptr[n] - ebase : 0;
  }
  __syncthreads();
  for (int i = tid; i < cnt; i += 1024) {
    uint2 p = bpack[ebase + i];
    int pos = atomicAdd(&lcur[(int)p.y - nbase], 1);
    if (pos < MAXBE) lsrc[pos] = (int)p.x;
  }
  __syncthreads();
  for (int i = tid; i < cnt; i += 1024) esrc[ebase + i] = lsrc[i];
}

// ---------------- gather agg v4: 4 nodes/wave, 16 lanes x uint4 (16B) each ----------------
// Degree-sorted perm -> the 4 nodes per wave have near-equal degree.
// Block 0 zeroes the BN stat accumulators.
__global__ __launch_bounds__(512) void agg_csr_kernel(const ushort* __restrict__ xb,
                                                      const int* __restrict__ rowptr,
                                                      const int* __restrict__ esrc,
                                                      const float* __restrict__ invdeg,
                                                      const int* __restrict__ perm,
                                                      ushort* __restrict__ aggb,
                                                      float* __restrict__ colsum,
                                                      float* __restrict__ colsumsq) {
  if (blockIdx.x == 0 && threadIdx.x < 2 * HD) {
    if (threadIdx.x < HD) colsum[threadIdx.x] = 0.f;
    else colsumsq[threadIdx.x - HD] = 0.f;
  }
  int wid = (blockIdx.x * 512 + threadIdx.x) >> 6;
  int lane = threadIdx.x & 63;
  int slot = wid * 4 + (lane >> 4);
  int sub = lane & 15;
  if (slot >= NN) return;
  int node = perm[slot];
  int start = rowptr[node], end = rowptr[node + 1];
  float a0 = 0.f, a1 = 0.f, a2 = 0.f, a3 = 0.f, a4 = 0.f, a5 = 0.f, a6 = 0.f, a7 = 0.f;
  int e = start;
  for (; e + 4 <= end; e += 4) {
    int s0 = esrc[e], s1 = esrc[e + 1], s2 = esrc[e + 2], s3 = esrc[e + 3];
    uint4 u0 = *(const uint4*)((const char*)xb + (size_t)s0 * 256 + sub * 16);
    uint4 u1 = *(const uint4*)((const char*)xb + (size_t)s1 * 256 + sub * 16);
    uint4 u2 = *(const uint4*)((const char*)xb + (size_t)s2 * 256 + sub * 16);
    uint4 u3 = *(const uint4*)((const char*)xb + (size_t)s3 * 256 + sub * 16);
    a0 += (bflo(u0.x) + bflo(u1.x)) + (bflo(u2.x) + bflo(u3.x));
    a1 += (bfhi(u0.x) + bfhi(u1.x)) + (bfhi(u2.x) + bfhi(u3.x));
    a2 += (bflo(u0.y) + bflo(u1.y)) + (bflo(u2.y) + bflo(u3.y));
    a3 += (bfhi(u0.y) + bfhi(u1.y)) + (bfhi(u2.y) + bfhi(u3.y));
    a4 += (bflo(u0.z) + bflo(u1.z)) + (bflo(u2.z) + bflo(u3.z));
    a5 += (bfhi(u0.z) + bfhi(u1.z)) + (bfhi(u2.z) + bfhi(u3.z));
    a6 += (bflo(u0.w) + bflo(u1.w)) + (bflo(u2.w) + bflo(u3.w));
    a7 += (bfhi(u0.w) + bfhi(u1.w)) + (bfhi(u2.w) + bfhi(u3.w));
  }
  for (; e < end; ++e) {
    uint4 u = *(const uint4*)((const char*)xb + (size_t)esrc[e] * 256 + sub * 16);
    a0 += bflo(u.x); a1 += bfhi(u.x);
    a2 += bflo(u.y); a3 += bfhi(u.y);
    a4 += bflo(u.z); a5 += bfhi(u.z);
    a6 += bflo(u.w); a7 += bfhi(u.w);
  }
  float id = invdeg[node];
  uint4 o;
  o.x = pack_bf16(a0 * id, a1 * id);
  o.y = pack_bf16(a2 * id, a3 * id);
  o.z = pack_bf16(a4 * id, a5 * id);
  o.w = pack_bf16(a6 * id, a7 * id);
  *(uint4*)((char*)aggb + (size_t)node * 256 + sub * 16) = o;
}

// ---------------- MFMA: pre = L2norm([aggb|xb] @ [Wl|Wr]^T + bl), BN stats ----------------
__global__ __launch_bounds__(512, 4) void mfma_pre_kernel(
    const ushort* __restrict__ aggb, const ushort* __restrict__ xb,
    const unsigned* __restrict__ wpackL, const float* __restrict__ bl,
    uint4* __restrict__ prebn,
    float* __restrict__ colsum, float* __restrict__ colsumsq) {
  __shared__ unsigned Bsw[16384];   // 64 KB
  __shared__ float lsum[HD], lsq[HD];
  const int tid = threadIdx.x;
  {
    const uint4* s = (const uint4*)wpackL;
    uint4* d = (uint4*)Bsw;
#pragma unroll
    for (int i = 0; i < 8; ++i) d[tid + i * 512] = s[tid + i * 512];
  }
  if (tid < HD) { lsum[tid] = 0.f; lsq[tid] = 0.f; }

  const int wave = tid >> 6, lane = tid & 63;
  const int lhi = lane >> 4, llo = lane & 15;
  int arow = blockIdx.x * 128 + wave * 16 + llo;
  if (arow >= NN) arow = NN - 1;
  const size_t rb = (size_t)arow * 256;

  uint4 areg[8];
#pragma unroll
  for (int ks = 0; ks < 4; ++ks) {
    areg[ks]     = *(const uint4*)((const char*)aggb + rb + ks * 64 + lhi * 16);
    areg[ks + 4] = *(const uint4*)((const char*)xb   + rb + ks * 64 + lhi * 16);
  }

  f32x4 acc[8];
#pragma unroll
  for (int ct = 0; ct < 8; ++ct) {
    float b = bl[ct * 16 + llo];
    acc[ct] = (f32x4){b, b, b, b};
  }
  __syncthreads();

#pragma unroll
  for (int ks = 0; ks < 8; ++ks) {
    bf16x8 a = __builtin_bit_cast(bf16x8, areg[ks]);
#pragma unroll
    for (int ct = 0; ct < 8; ++ct) {
      int bcol = ct * 16 + llo;
      unsigned bb = (unsigned)(bcol * 512 + ks * 64 + lhi * 16) ^ (unsigned)((bcol & 7) << 4);
      bf16x8 b = *(const bf16x8*)((const char*)Bsw + bb);
      acc[ct] = __builtin_amdgcn_mfma_f32_16x16x32_bf16(a, b, acc[ct], 0, 0, 0);
    }
  }

  float cs[8] = {0, 0, 0, 0, 0, 0, 0, 0}, cq[8] = {0, 0, 0, 0, 0, 0, 0, 0};
#pragma unroll
  for (int r = 0; r < 4; ++r) {
    int orow = blockIdx.x * 128 + wave * 16 + lhi * 4 + r;
    float p[8];
    float ss = 0.f;
#pragma unroll
    for (int ct = 0; ct < 8; ++ct) { p[ct] = acc[ct][r]; ss += p[ct] * p[ct]; }
#pragma unroll
    for (int m = 8; m >= 1; m >>= 1) ss += __shfl_xor(ss, m, 64);
    float inv = 1.0f / fmaxf(sqrtf(ss), EPS_NORM);
#pragma unroll
    for (int ct = 0; ct < 8; ++ct) p[ct] *= inv;
    uint4 o;
    o.x = pack_bf16(p[0], p[1]);
    o.y = pack_bf16(p[2], p[3]);
    o.z = pack_bf16(p[4], p[5]);
    o.w = pack_bf16(p[6], p[7]);
    prebn[((size_t)blockIdx.x * 32 + wave * 4 + r) * 64 + lane] = o;
    if (orow < NN) {
#pragma unroll
      for (int ct = 0; ct < 8; ++ct) { cs[ct] += p[ct]; cq[ct] += p[ct] * p[ct]; }
    }
  }
#pragma unroll
  for (int ct = 0; ct < 8; ++ct) {
    atomicAdd(&lsum[ct * 16 + llo], cs[ct]);
    atomicAdd(&lsq[ct * 16 + llo], cq[ct]);
  }
  __syncthreads();
  if (tid < HD) {
    atomicAdd(&colsum[tid], lsum[tid]);
    atomicAdd(&colsumsq[tid], lsq[tid]);
  }
}

// ---------------- MFMA + inline BN finalize: out = lrelu(BN(pre)) + xb@Ws^T + bs ----------------
__global__ __launch_bounds__(512, 4) void res_mfma_kernel(
    ushort* __restrict__ xb, const uint4* __restrict__ prebn,
    const unsigned* __restrict__ wpackS, const float* __restrict__ bs,
    const float* __restrict__ colsum, const float* __restrict__ colsumsq,
    const float* __restrict__ gamma, const float* __restrict__ beta,
    float* __restrict__ outf, int last) {
  __shared__ unsigned Bsw[8192];   // 32 KB
  __shared__ float lscale[HD], lshift[HD];
  const int tid = threadIdx.x;
  {
    const uint4* s = (const uint4*)wpackS;
    uint4* d = (uint4*)Bsw;
#pragma unroll
    for (int i = 0; i < 4; ++i) d[tid + i * 512] = s[tid + i * 512];
  }
  if (tid < HD) {
    float mu = colsum[tid] * (1.0f / NN);
    float ex2 = colsumsq[tid] * (1.0f / NN);
    float var = ex2 - mu * mu;
    float sc = gamma[tid] * rsqrtf(var + EPS_BN);
    lscale[tid] = sc;
    lshift[tid] = beta[tid] - mu * sc;
  }

  const int wave = tid >> 6, lane = tid & 63;
  const int lhi = lane >> 4, llo = lane & 15;
  int arow = blockIdx.x * 128 + wave * 16 + llo;
  if (arow >= NN) arow = NN - 1;
  const size_t rb = (size_t)arow * 256;

  uint4 areg[4];
#pragma unroll
  for (int ks = 0; ks < 4; ++ks)
    areg[ks] = *(const uint4*)((const char*)xb + rb + ks * 64 + lhi * 16);
  uint4 pv4[4];
#pragma unroll
  for (int r = 0; r < 4; ++r)
    pv4[r] = prebn[((size_t)blockIdx.x * 32 + wave * 4 + r) * 64 + lane];

  f32x4 acc[8];
#pragma unroll
  for (int ct = 0; ct < 8; ++ct) {
    float b = bs[ct * 16 + llo];
    acc[ct] = (f32x4){b, b, b, b};
  }
  __syncthreads();

  float sc8[8], sh8[8];
#pragma unroll
  for (int ct = 0; ct < 8; ++ct) {
    int C = ct * 16 + llo;
    sc8[ct] = lscale[C];
    sh8[ct] = lshift[C];
  }

#pragma unroll
  for (int ks = 0; ks < 4; ++ks) {
    bf16x8 a = __builtin_bit_cast(bf16x8, areg[ks]);
#pragma unroll
    for (int ct = 0; ct < 8; ++ct) {
      int bcol = ct * 16 + llo;
      unsigned bb = (unsigned)(bcol * 256 + ks * 64 + lhi * 16) ^ (unsigned)((bcol & 7) << 4);
      bf16x8 b = *(const bf16x8*)((const char*)Bsw + bb);
      acc[ct] = __builtin_amdgcn_mfma_f32_16x16x32_bf16(a, b, acc[ct], 0, 0, 0);
    }
  }

#pragma unroll
  for (int r = 0; r < 4; ++r) {
    int orow = blockIdx.x * 128 + wave * 16 + lhi * 4 + r;
    if (orow < NN) {
      const unsigned* pw = (const unsigned*)&pv4[r];
#pragma unroll
      for (int ct = 0; ct < 8; ++ct) {
        unsigned w = pw[ct >> 1];
        float pv = (ct & 1) ? bfhi(w) : bflo(w);
        float v = pv * sc8[ct] + sh8[ct];
        v = v >= 0.f ? v : NEG_SLOPE * v;
        float o = v + acc[ct][r];
        if (last) outf[(size_t)orow * HD + ct * 16 + llo] = o;
        else      xb[(size_t)orow * HD + ct * 16 + llo] = bf16of(o);
      }
    }
  }
}

extern "C" void kernel_launch(void* const* d_in, const int* in_sizes, int n_in,
                              void* d_out, int out_size, void* d_ws, size_t ws_size,
                              hipStream_t stream) {
  const float* x0    = (const float*)d_in[0];
  const int*   ei    = (const int*)d_in[1];
  const float* Wl    = (const float*)d_in[2];
  const float* bl    = (const float*)d_in[3];
  const float* Wr    = (const float*)d_in[4];
  const float* gamma = (const float*)d_in[5];
  const float* beta  = (const float*)d_in[6];
  const float* Wsm   = (const float*)d_in[7];
  const float* bs    = (const float*)d_in[8];
  float* out = (float*)d_out;

  char* w = (char*)d_ws;
  ushort* aggb = (ushort*)w;        w += (size_t)NN * HD * 2;            // 12.8 MB
  ushort* xb   = (ushort*)w;        w += (size_t)NN * HD * 2;            // 12.8 MB
  uint4* prebn = (uint4*)w;         w += (size_t)NTILES * 32 * 64 * 16;  // 12.81 MB
  unsigned* wpackL = (unsigned*)w;  w += (size_t)NL * 16384 * 4;         // 192 KB
  unsigned* wpackS = (unsigned*)w;  w += 8192 * 4;                       // 32 KB
  float* invdeg = (float*)w;        w += (size_t)NN * 4;
  float* colsum = (float*)w;        w += HD * 4;
  float* colsumsq = (float*)w;      w += HD * 4;
  int* degi = (int*)w;              w += (size_t)NN * 4;
  int* rowptr = (int*)w;            w += (size_t)(NN + 1) * 4;
  int* perm = (int*)w;              w += (size_t)NN * 4;
  int* bcursor = (int*)w;           w += (size_t)(NB + 8) * 4;
  int* blocksum = (int*)w;          w += SCAN_BLOCKS * 4;
  int* blockoff = (int*)w;          w += SCAN_BLOCKS * 4;
  int* done_counter = (int*)w;      w += 16;
  uint2* bpack = (uint2*)w;         w += (size_t)NE * 8;                 // 6.4 MB
  int* esrc = (int*)w;              w += (size_t)NE * 4;                 // 3.2 MB

  const int* srcp = ei;
  const int* dstp = ei + NE;

  // one-time: CSR build (low-write-amp two-phase sort) + bf16 convert + weight pre-pack
  hipMemsetAsync(degi, 0, NN * sizeof(int), stream);
  prep_kernel<<<PREP_TOTAL_B, 256, 0, stream>>>(dstp, x0, Wl, Wr, Wsm,
                                                degi, xb, wpackL, wpackS, done_counter);
  bsum_scan_kernel<<<SCAN_BLOCKS, 256, 0, stream>>>(degi, blocksum, blockoff, rowptr,
                                                    done_counter);
  chunkscan_kernel<<<SCAN_BLOCKS, 256, 0, stream>>>(degi, blockoff, rowptr, bcursor, invdeg);
  degsort_kernel<<<1, 1024, 0, stream>>>(degi, perm);
  bucketB_kernel<<<(NE + 1023) / 1024, 1024, 0, stream>>>(srcp, dstp, bcursor, bpack);
  bucketC_kernel<<<NB, 1024, 0, stream>>>(rowptr, bpack, esrc);

  const int aggBlocks = (((NN + 3) / 4) * 64 + 511) / 512;   // 4 nodes/wave
  for (int l = 0; l < NL; ++l) {
    agg_csr_kernel<<<aggBlocks, 512, 0, stream>>>(xb, rowptr, esrc, invdeg, perm, aggb,
                                                  colsum, colsumsq);
    mfma_pre_kernel<<<NTILES, 512, 0, stream>>>(aggb, xb, wpackL + (size_t)l * 16384,
                                                bl + (size_t)l * HD, prebn, colsum, colsumsq);
    res_mfma_kernel<<<NTILES, 512, 0, stream>>>(xb, prebn, wpackS, bs,
                                                colsum, colsumsq,
                                                gamma + (size_t)l * HD, beta + (size_t)l * HD,
                                                out, l == NL - 1 ? 1 : 0);
  }
}

// Round 17
// 306.878 us; speedup vs baseline: 1.1069x; 1.1069x over previous
//
#include <hip/hip_runtime.h>
#include <hip/hip_bf16.h>
#include <stdint.h>

#define NN 50000
#define NE 800000
#define HD 128
#define NL 3
#define EPS_BN 1e-5f
#define EPS_NORM 1e-12f
#define NEG_SLOPE 0.1f

#define SCAN_CHUNK 256
#define SCAN_BLOCKS ((NN + SCAN_CHUNK - 1) / SCAN_CHUNK)   // 196
#define NTILES ((NN + 127) / 128)                          // 391

#define BSH 9                                   // coarse bucket = dst >> 9 (512 nodes)
#define NB ((NN + (1 << BSH) - 1) >> BSH)       // 98 buckets
#define MAXBE 9728                              // per-bucket edge cap

typedef __attribute__((ext_vector_type(8))) short bf16x8;
typedef __attribute__((ext_vector_type(4))) float f32x4;

static __device__ __forceinline__ unsigned pack_bf16(float a, float b) {
  unsigned ua = __builtin_bit_cast(unsigned, a);
  unsigned ub = __builtin_bit_cast(unsigned, b);
  ua = (ua + 0x7fffu + ((ua >> 16) & 1u)) >> 16;   // RNE
  ub = (ub + 0x7fffu + ((ub >> 16) & 1u)) >> 16;
  return ua | (ub << 16);
}
static __device__ __forceinline__ ushort bf16of(float f) {
  unsigned u = __builtin_bit_cast(unsigned, f);
  u = (u + 0x7fffu + ((u >> 16) & 1u)) >> 16;
  return (ushort)u;
}
static __device__ __forceinline__ float bflo(unsigned u) { return __builtin_bit_cast(float, u << 16); }
static __device__ __forceinline__ float bfhi(unsigned u) { return __builtin_bit_cast(float, u & 0xffff0000u); }

// ---------------- CSR build ----------------
__global__ __launch_bounds__(256) void hist_kernel(const int* __restrict__ dst, int* __restrict__ degi) {
  int i = blockIdx.x * 256 + threadIdx.x;
  if (i < NE) atomicAdd(&degi[dst[i]], 1);
}

__global__ __launch_bounds__(256) void blocksum_kernel(const int* __restrict__ degi,
                                                       int* __restrict__ blocksum) {
  __shared__ int sh[256];
  int t = threadIdx.x;
  int i = blockIdx.x * 256 + t;
  sh[t] = (i < NN) ? degi[i] : 0;
  __syncthreads();
  for (int off = 128; off >= 1; off >>= 1) {
    if (t < off) sh[t] += sh[t + off];
    __syncthreads();
  }
  if (t == 0) blocksum[blockIdx.x] = sh[0];
}

__global__ __launch_bounds__(256) void blockscan_kernel(int* __restrict__ blocksum,
                                                        int* __restrict__ blockoff,
                                                        int* __restrict__ rowptr) {
  __shared__ int sh[256];
  int t = threadIdx.x;
  int v = (t < SCAN_BLOCKS) ? blocksum[t] : 0;
  sh[t] = v;
  __syncthreads();
  for (int off = 1; off < 256; off <<= 1) {
    int u = (t >= off) ? sh[t - off] : 0;
    __syncthreads();
    sh[t] += u;
    __syncthreads();
  }
  if (t < SCAN_BLOCKS) blockoff[t] = sh[t] - v;
  if (t == 255) rowptr[NN] = sh[255];
}

// also seeds bcursor[c] = rowptr[c*512] for the bucket scatter
__global__ __launch_bounds__(256) void chunkscan_kernel(const int* __restrict__ degi,
                                                        const int* __restrict__ blockoff,
                                                        int* __restrict__ rowptr,
                                                        int* __restrict__ bcursor,
                                                        float* __restrict__ invdeg) {
  __shared__ int sh[256];
  int t = threadIdx.x;
  int i = blockIdx.x * 256 + t;
  int d = (i < NN) ? degi[i] : 0;
  sh[t] = d;
  __syncthreads();
  for (int off = 1; off < 256; off <<= 1) {
    int u = (t >= off) ? sh[t - off] : 0;
    __syncthreads();
    sh[t] += u;
    __syncthreads();
  }
  if (i < NN) {
    int pre = blockoff[blockIdx.x] + sh[t] - d;
    rowptr[i] = pre;
    if ((i & ((1 << BSH) - 1)) == 0) bcursor[i >> BSH] = pre;
    invdeg[i] = 1.0f / fmaxf((float)d, 1.0f);
  }
}

// ---------------- Phase B: group edges by coarse bucket (grouped runs -> low write amp) ----------------
__global__ __launch_bounds__(1024) void bucketB_kernel(const int* __restrict__ src,
                                                       const int* __restrict__ dst,
                                                       int* __restrict__ bcursor,
                                                       uint2* __restrict__ bpack) {
  __shared__ int hist[NB], lstart[NB], gbase[NB];
  __shared__ uint2 sdat[1024];
  const int tid = threadIdx.x;
  const int e = blockIdx.x * 1024 + tid;
  if (tid < NB) hist[tid] = 0;
  __syncthreads();
  int s = 0, d = 0, b = 0, myIdx = 0;
  bool valid = (e < NE);
  if (valid) {
    s = src[e];
    d = dst[e];
    b = d >> BSH;
    myIdx = atomicAdd(&hist[b], 1);
  }
  __syncthreads();
  if (tid == 0) {
    int run = 0;
    for (int i = 0; i < NB; ++i) { lstart[i] = run; run += hist[i]; }
  }
  __syncthreads();
  if (tid < NB && hist[tid] > 0) gbase[tid] = atomicAdd(&bcursor[tid], hist[tid]);
  __syncthreads();
  if (valid) sdat[lstart[b] + myIdx] = make_uint2((unsigned)s, (unsigned)d);
  __syncthreads();
  int tot = lstart[NB - 1] + hist[NB - 1];
  if (tid < tot) {
    uint2 p = sdat[tid];
    int bb = (int)(p.y >> BSH);
    bpack[gbase[bb] + (tid - lstart[bb])] = p;
  }
}

// ---------------- Phase C: per-bucket LDS counting sort -> contiguous esrc write ----------------
__global__ __launch_bounds__(1024) void bucketC_kernel(const int* __restrict__ rowptr,
                                                       const uint2* __restrict__ bpack,
                                                       int* __restrict__ esrc) {
  __shared__ int lcur[1 << BSH];
  __shared__ int lsrc[MAXBE];
  const int c = blockIdx.x, tid = threadIdx.x;
  const int nbase = c << BSH;
  const int nend = min(nbase + (1 << BSH), NN);
  const int ebase = rowptr[nbase];
  const int cnt = rowptr[nend] - ebase;
  if (tid < (1 << BSH)) {
    int n = nbase + tid;
    lcur[tid] = (n < nend) ? rowptr[n] - ebase : 0;
  }
  __syncthreads();
  for (int i = tid; i < cnt; i += 1024) {
    uint2 p = bpack[ebase + i];
    int pos = atomicAdd(&lcur[(int)p.y - nbase], 1);
    if (pos < MAXBE) lsrc[pos] = (int)p.x;
  }
  __syncthreads();
  for (int i = tid; i < cnt; i += 1024) esrc[ebase + i] = lsrc[i];
}

// ---------------- f32 -> bf16 convert ----------------
__global__ __launch_bounds__(256) void tobf16_kernel(const float* __restrict__ x, ushort* __restrict__ xb) {
  int i = blockIdx.x * 256 + threadIdx.x;
  if (i < NN * 64) {
    float2 f = *(const float2*)(x + (size_t)i * 2);
    *(unsigned*)(xb + (size_t)i * 2) = pack_bf16(f.x, f.y);
  }
}

// ---------------- one-time weight pre-pack (swizzled bf16 LDS images) ----------------
__global__ __launch_bounds__(256) void packW_kernel(const float* __restrict__ Wl,
                                                    const float* __restrict__ Wr,
                                                    const float* __restrict__ Wsm,
                                                    unsigned* __restrict__ wpackL,
                                                    unsigned* __restrict__ wpackS) {
  int i = blockIdx.x * 256 + threadIdx.x;
  if (i < NL * 16384) {
    int l = i >> 14, rem = i & 16383;
    int c = rem >> 7, kp = rem & 127;
    int k2 = kp * 2;
    float f0, f1;
    if (k2 < HD) { const float* W = Wl + (size_t)l * HD * HD + c * HD + k2; f0 = W[0]; f1 = W[1]; }
    else         { const float* W = Wr + (size_t)l * HD * HD + c * HD + (k2 - HD); f0 = W[0]; f1 = W[1]; }
    unsigned ba = (unsigned)(c * 512 + kp * 4) ^ (unsigned)((c & 7) << 4);
    *(unsigned*)((char*)(wpackL + (size_t)l * 16384) + ba) = pack_bf16(f0, f1);
  } else if (i < NL * 16384 + 8192) {
    int j = i - NL * 16384;
    int c = j >> 6, kp = j & 63;
    int k2 = kp * 2;
    unsigned ba = (unsigned)(c * 256 + kp * 4) ^ (unsigned)((c & 7) << 4);
    *(unsigned*)((char*)wpackS + ba) = pack_bf16(Wsm[c * HD + k2], Wsm[c * HD + k2 + 1]);
  }
}

// ---------------- gather agg v4: 4 nodes/wave, 16 lanes x uint4 (16B) each ----------------
// Block 0 zeroes the BN stat accumulators.
__global__ __launch_bounds__(512) void agg_csr_kernel(const ushort* __restrict__ xb,
                                                      const int* __restrict__ rowptr,
                                                      const int* __restrict__ esrc,
                                                      const float* __restrict__ invdeg,
                                                      ushort* __restrict__ aggb,
                                                      float* __restrict__ colsum,
                                                      float* __restrict__ colsumsq) {
  if (blockIdx.x == 0 && threadIdx.x < 2 * HD) {
    if (threadIdx.x < HD) colsum[threadIdx.x] = 0.f;
    else colsumsq[threadIdx.x - HD] = 0.f;
  }
  int wid = (blockIdx.x * 512 + threadIdx.x) >> 6;
  int lane = threadIdx.x & 63;
  int node = wid * 4 + (lane >> 4);
  int sub = lane & 15;
  if (node >= NN) return;
  int start = rowptr[node], end = rowptr[node + 1];
  float a0 = 0.f, a1 = 0.f, a2 = 0.f, a3 = 0.f, a4 = 0.f, a5 = 0.f, a6 = 0.f, a7 = 0.f;
  int e = start;
  for (; e + 4 <= end; e += 4) {
    int s0 = esrc[e], s1 = esrc[e + 1], s2 = esrc[e + 2], s3 = esrc[e + 3];
    uint4 u0 = *(const uint4*)((const char*)xb + (size_t)s0 * 256 + sub * 16);
    uint4 u1 = *(const uint4*)((const char*)xb + (size_t)s1 * 256 + sub * 16);
    uint4 u2 = *(const uint4*)((const char*)xb + (size_t)s2 * 256 + sub * 16);
    uint4 u3 = *(const uint4*)((const char*)xb + (size_t)s3 * 256 + sub * 16);
    a0 += (bflo(u0.x) + bflo(u1.x)) + (bflo(u2.x) + bflo(u3.x));
    a1 += (bfhi(u0.x) + bfhi(u1.x)) + (bfhi(u2.x) + bfhi(u3.x));
    a2 += (bflo(u0.y) + bflo(u1.y)) + (bflo(u2.y) + bflo(u3.y));
    a3 += (bfhi(u0.y) + bfhi(u1.y)) + (bfhi(u2.y) + bfhi(u3.y));
    a4 += (bflo(u0.z) + bflo(u1.z)) + (bflo(u2.z) + bflo(u3.z));
    a5 += (bfhi(u0.z) + bfhi(u1.z)) + (bfhi(u2.z) + bfhi(u3.z));
    a6 += (bflo(u0.w) + bflo(u1.w)) + (bflo(u2.w) + bflo(u3.w));
    a7 += (bfhi(u0.w) + bfhi(u1.w)) + (bfhi(u2.w) + bfhi(u3.w));
  }
  for (; e < end; ++e) {
    uint4 u = *(const uint4*)((const char*)xb + (size_t)esrc[e] * 256 + sub * 16);
    a0 += bflo(u.x); a1 += bfhi(u.x);
    a2 += bflo(u.y); a3 += bfhi(u.y);
    a4 += bflo(u.z); a5 += bfhi(u.z);
    a6 += bflo(u.w); a7 += bfhi(u.w);
  }
  float id = invdeg[node];
  uint4 o;
  o.x = pack_bf16(a0 * id, a1 * id);
  o.y = pack_bf16(a2 * id, a3 * id);
  o.z = pack_bf16(a4 * id, a5 * id);
  o.w = pack_bf16(a6 * id, a7 * id);
  *(uint4*)((char*)aggb + (size_t)node * 256 + sub * 16) = o;
}

// ---------------- MFMA: pre = L2norm([aggb|xb] @ [Wl|Wr]^T + bl), BN stats ----------------
__global__ __launch_bounds__(512, 4) void mfma_pre_kernel(
    const ushort* __restrict__ aggb, const ushort* __restrict__ xb,
    const unsigned* __restrict__ wpackL, const float* __restrict__ bl,
    uint4* __restrict__ prebn,
    float* __restrict__ colsum, float* __restrict__ colsumsq) {
  __shared__ unsigned Bsw[16384];   // 64 KB
  __shared__ float lsum[HD], lsq[HD];
  const int tid = threadIdx.x;
  {
    const uint4* s = (const uint4*)wpackL;
    uint4* d = (uint4*)Bsw;
#pragma unroll
    for (int i = 0; i < 8; ++i) d[tid + i * 512] = s[tid + i * 512];
  }
  if (tid < HD) { lsum[tid] = 0.f; lsq[tid] = 0.f; }

  const int wave = tid >> 6, lane = tid & 63;
  const int lhi = lane >> 4, llo = lane & 15;
  int arow = blockIdx.x * 128 + wave * 16 + llo;
  if (arow >= NN) arow = NN - 1;
  const size_t rb = (size_t)arow * 256;

  uint4 areg[8];
#pragma unroll
  for (int ks = 0; ks < 4; ++ks) {
    areg[ks]     = *(const uint4*)((const char*)aggb + rb + ks * 64 + lhi * 16);
    areg[ks + 4] = *(const uint4*)((const char*)xb   + rb + ks * 64 + lhi * 16);
  }

  f32x4 acc[8];
#pragma unroll
  for (int ct = 0; ct < 8; ++ct) {
    float b = bl[ct * 16 + llo];
    acc[ct] = (f32x4){b, b, b, b};
  }
  __syncthreads();

#pragma unroll
  for (int ks = 0; ks < 8; ++ks) {
    bf16x8 a = __builtin_bit_cast(bf16x8, areg[ks]);
#pragma unroll
    for (int ct = 0; ct < 8; ++ct) {
      int bcol = ct * 16 + llo;
      unsigned bb = (unsigned)(bcol * 512 + ks * 64 + lhi * 16) ^ (unsigned)((bcol & 7) << 4);
      bf16x8 b = *(const bf16x8*)((const char*)Bsw + bb);
      acc[ct] = __builtin_amdgcn_mfma_f32_16x16x32_bf16(a, b, acc[ct], 0, 0, 0);
    }
  }

  float cs[8] = {0, 0, 0, 0, 0, 0, 0, 0}, cq[8] = {0, 0, 0, 0, 0, 0, 0, 0};
#pragma unroll
  for (int r = 0; r < 4; ++r) {
    int orow = blockIdx.x * 128 + wave * 16 + lhi * 4 + r;
    float p[8];
    float ss = 0.f;
#pragma unroll
    for (int ct = 0; ct < 8; ++ct) { p[ct] = acc[ct][r]; ss += p[ct] * p[ct]; }
#pragma unroll
    for (int m = 8; m >= 1; m >>= 1) ss += __shfl_xor(ss, m, 64);
    float inv = 1.0f / fmaxf(sqrtf(ss), EPS_NORM);
#pragma unroll
    for (int ct = 0; ct < 8; ++ct) p[ct] *= inv;
    uint4 o;
    o.x = pack_bf16(p[0], p[1]);
    o.y = pack_bf16(p[2], p[3]);
    o.z = pack_bf16(p[4], p[5]);
    o.w = pack_bf16(p[6], p[7]);
    prebn[((size_t)blockIdx.x * 32 + wave * 4 + r) * 64 + lane] = o;
    if (orow < NN) {
#pragma unroll
      for (int ct = 0; ct < 8; ++ct) { cs[ct] += p[ct]; cq[ct] += p[ct] * p[ct]; }
    }
  }
#pragma unroll
  for (int ct = 0; ct < 8; ++ct) {
    atomicAdd(&lsum[ct * 16 + llo], cs[ct]);
    atomicAdd(&lsq[ct * 16 + llo], cq[ct]);
  }
  __syncthreads();
  if (tid < HD) {
    atomicAdd(&colsum[tid], lsum[tid]);
    atomicAdd(&colsumsq[tid], lsq[tid]);
  }
}

// ---------------- MFMA + inline BN finalize: out = lrelu(BN(pre)) + xb@Ws^T + bs ----------------
__global__ __launch_bounds__(512, 4) void res_mfma_kernel(
    ushort* __restrict__ xb, const uint4* __restrict__ prebn,
    const unsigned* __restrict__ wpackS, const float* __restrict__ bs,
    const float* __restrict__ colsum, const float* __restrict__ colsumsq,
    const float* __restrict__ gamma, const float* __restrict__ beta,
    float* __restrict__ outf, int last) {
  __shared__ unsigned Bsw[8192];   // 32 KB
  __shared__ float lscale[HD], lshift[HD];
  const int tid = threadIdx.x;
  {
    const uint4* s = (const uint4*)wpackS;
    uint4* d = (uint4*)Bsw;
#pragma unroll
    for (int i = 0; i < 4; ++i) d[tid + i * 512] = s[tid + i * 512];
  }
  if (tid < HD) {
    float mu = colsum[tid] * (1.0f / NN);
    float ex2 = colsumsq[tid] * (1.0f / NN);
    float var = ex2 - mu * mu;
    float sc = gamma[tid] * rsqrtf(var + EPS_BN);
    lscale[tid] = sc;
    lshift[tid] = beta[tid] - mu * sc;
  }

  const int wave = tid >> 6, lane = tid & 63;
  const int lhi = lane >> 4, llo = lane & 15;
  int arow = blockIdx.x * 128 + wave * 16 + llo;
  if (arow >= NN) arow = NN - 1;
  const size_t rb = (size_t)arow * 256;

  uint4 areg[4];
#pragma unroll
  for (int ks = 0; ks < 4; ++ks)
    areg[ks] = *(const uint4*)((const char*)xb + rb + ks * 64 + lhi * 16);
  uint4 pv4[4];
#pragma unroll
  for (int r = 0; r < 4; ++r)
    pv4[r] = prebn[((size_t)blockIdx.x * 32 + wave * 4 + r) * 64 + lane];

  f32x4 acc[8];
#pragma unroll
  for (int ct = 0; ct < 8; ++ct) {
    float b = bs[ct * 16 + llo];
    acc[ct] = (f32x4){b, b, b, b};
  }
  __syncthreads();

  float sc8[8], sh8[8];
#pragma unroll
  for (int ct = 0; ct < 8; ++ct) {
    int C = ct * 16 + llo;
    sc8[ct] = lscale[C];
    sh8[ct] = lshift[C];
  }

#pragma unroll
  for (int ks = 0; ks < 4; ++ks) {
    bf16x8 a = __builtin_bit_cast(bf16x8, areg[ks]);
#pragma unroll
    for (int ct = 0; ct < 8; ++ct) {
      int bcol = ct * 16 + llo;
      unsigned bb = (unsigned)(bcol * 256 + ks * 64 + lhi * 16) ^ (unsigned)((bcol & 7) << 4);
      bf16x8 b = *(const bf16x8*)((const char*)Bsw + bb);
      acc[ct] = __builtin_amdgcn_mfma_f32_16x16x32_bf16(a, b, acc[ct], 0, 0, 0);
    }
  }

#pragma unroll
  for (int r = 0; r < 4; ++r) {
    int orow = blockIdx.x * 128 + wave * 16 + lhi * 4 + r;
    if (orow < NN) {
      const unsigned* pw = (const unsigned*)&pv4[r];
#pragma unroll
      for (int ct = 0; ct < 8; ++ct) {
        unsigned w = pw[ct >> 1];
        float pv = (ct & 1) ? bfhi(w) : bflo(w);
        float v = pv * sc8[ct] + sh8[ct];
        v = v >= 0.f ? v : NEG_SLOPE * v;
        float o = v + acc[ct][r];
        if (last) outf[(size_t)orow * HD + ct * 16 + llo] = o;
        else      xb[(size_t)orow * HD + ct * 16 + llo] = bf16of(o);
      }
    }
  }
}

extern "C" void kernel_launch(void* const* d_in, const int* in_sizes, int n_in,
                              void* d_out, int out_size, void* d_ws, size_t ws_size,
                              hipStream_t stream) {
  const float* x0    = (const float*)d_in[0];
  const int*   ei    = (const int*)d_in[1];
  const float* Wl    = (const float*)d_in[2];
  const float* bl    = (const float*)d_in[3];
  const float* Wr    = (const float*)d_in[4];
  const float* gamma = (const float*)d_in[5];
  const float* beta  = (const float*)d_in[6];
  const float* Wsm   = (const float*)d_in[7];
  const float* bs    = (const float*)d_in[8];
  float* out = (float*)d_out;

  char* w = (char*)d_ws;
  ushort* aggb = (ushort*)w;        w += (size_t)NN * HD * 2;            // 12.8 MB
  ushort* xb   = (ushort*)w;        w += (size_t)NN * HD * 2;            // 12.8 MB
  uint4* prebn = (uint4*)w;         w += (size_t)NTILES * 32 * 64 * 16;  // 12.81 MB
  unsigned* wpackL = (unsigned*)w;  w += (size_t)NL * 16384 * 4;         // 192 KB
  unsigned* wpackS = (unsigned*)w;  w += 8192 * 4;                       // 32 KB
  float* invdeg = (float*)w;        w += (size_t)NN * 4;
  float* colsum = (float*)w;        w += HD * 4;
  float* colsumsq = (float*)w;      w += HD * 4;
  int* degi = (int*)w;              w += (size_t)NN * 4;
  int* rowptr = (int*)w;            w += (size_t)(NN + 1) * 4;
  int* bcursor = (int*)w;           w += (size_t)(NB + 8) * 4;
  int* blocksum = (int*)w;          w += SCAN_BLOCKS * 4;
  int* blockoff = (int*)w;          w += SCAN_BLOCKS * 4;
  uint2* bpack = (uint2*)w;         w += (size_t)NE * 8;                 // 6.4 MB
  int* esrc = (int*)w;              w += (size_t)NE * 4;                 // 3.2 MB

  const int* srcp = ei;
  const int* dstp = ei + NE;

  // one-time: CSR build (low-write-amp two-phase sort) + bf16 convert + weight pre-pack
  hipMemsetAsync(degi, 0, NN * sizeof(int), stream);
  hist_kernel<<<(NE + 255) / 256, 256, 0, stream>>>(dstp, degi);
  blocksum_kernel<<<SCAN_BLOCKS, 256, 0, stream>>>(degi, blocksum);
  blockscan_kernel<<<1, 256, 0, stream>>>(blocksum, blockoff, rowptr);
  chunkscan_kernel<<<SCAN_BLOCKS, 256, 0, stream>>>(degi, blockoff, rowptr, bcursor, invdeg);
  bucketB_kernel<<<(NE + 1023) / 1024, 1024, 0, stream>>>(srcp, dstp, bcursor, bpack);
  bucketC_kernel<<<NB, 1024, 0, stream>>>(rowptr, bpack, esrc);
  tobf16_kernel<<<(NN * 64 + 255) / 256, 256, 0, stream>>>(x0, xb);
  packW_kernel<<<(NL * 16384 + 8192 + 255) / 256, 256, 0, stream>>>(Wl, Wr, Wsm, wpackL, wpackS);

  const int aggBlocks = (((NN + 3) / 4) * 64 + 511) / 512;   // 4 nodes/wave
  for (int l = 0; l < NL; ++l) {
    agg_csr_kernel<<<aggBlocks, 512, 0, stream>>>(xb, rowptr, esrc, invdeg, aggb,
                                                  colsum, colsumsq);
    mfma_pre_kernel<<<NTILES, 512, 0, stream>>>(aggb, xb, wpackL + (size_t)l * 16384,
                                                bl + (size_t)l * HD, prebn, colsum, colsumsq);
    res_mfma_kernel<<<NTILES, 512, 0, stream>>>(xb, prebn, wpackS, bs,
                                                colsum, colsumsq,
                                                gamma + (size_t)l * HD, beta + (size_t)l * HD,
                                                out, l == NL - 1 ? 1 : 0);
  }
}